// Round 7
// baseline (844.767 us; speedup 1.0000x reference)
//
#include <hip/hip_runtime.h>
#include <hip/hip_fp16.h>

#define N_NODES 30000
#define N_EDGES 240000
#define EMB     300
#define NPAD    30080   // 235 * 128
#define K1      320     // padded EMB (gemm1 K, agg cols, fp16)
#define NP1     640     // padded 2*EMB (gemm1 out cols = gemm2 K)
#define NP2     384     // gemm2 padded col count / h2 fp16 row stride
#define HSH     304     // h row stride in fp16 elements
#define LAYERS  5

typedef _Float16 half8 __attribute__((ext_vector_type(8)));
typedef __attribute__((ext_vector_type(4))) float floatx4;

// async 16B global->LDS (per-lane gptr, LDS dest = wave-uniform base + lane*16)
__device__ __forceinline__ void gload16(const void* g, void* l) {
  __builtin_amdgcn_global_load_lds(
      (const __attribute__((address_space(1))) unsigned int*)g,
      (__attribute__((address_space(3))) unsigned int*)l, 16, 0, 0);
}

// ---------------- weight conversion / transpose (fp16) ----------------
__global__ void conv_w1t_kernel(const float* __restrict__ W1, __half* __restrict__ w1t) {
  int idx = blockIdx.x * 256 + threadIdx.x;
  if (idx >= LAYERS * NP1 * K1) return;
  int l = idx / (NP1 * K1);
  int rem = idx % (NP1 * K1);
  int n = rem / K1, k = rem % K1;
  float v = (n < 2 * EMB && k < EMB) ? W1[(size_t)l * EMB * 2 * EMB + (size_t)k * 2 * EMB + n] : 0.f;
  w1t[idx] = __float2half(v);
}
__global__ void conv_w2t_kernel(const float* __restrict__ W2, __half* __restrict__ w2t) {
  int idx = blockIdx.x * 256 + threadIdx.x;
  if (idx >= LAYERS * NP2 * NP1) return;
  int l = idx / (NP2 * NP1);
  int rem = idx % (NP2 * NP1);
  int n = rem / NP1, k = rem % NP1;
  float v = (n < EMB && k < 2 * EMB) ? W2[(size_t)l * 2 * EMB * EMB + (size_t)k * EMB + n] : 0.f;
  w2t[idx] = __float2half(v);
}
// both bias pads in one dispatch
__global__ void conv_bias_kernel(const float* __restrict__ b1, const float* __restrict__ b2,
                                 float* __restrict__ b1p, float* __restrict__ b2p) {
  int idx = blockIdx.x * 256 + threadIdx.x;
  if (idx < LAYERS * NP1) {
    int l = idx / NP1, j = idx % NP1;
    b1p[idx] = (j < 2 * EMB) ? b1[l * 2 * EMB + j] : 0.f;
  } else {
    idx -= LAYERS * NP1;
    if (idx < LAYERS * NP2) {
      int l = idx / NP2, j = idx % NP2;
      b2p[idx] = (j < EMB) ? b2[l * EMB + j] : 0.f;
    }
  }
}

// ---------------- initial embedding (fp16 h) ----------------
__global__ __launch_bounds__(256)
void embed_kernel(const int* __restrict__ x, const float* __restrict__ emb1,
                  const float* __restrict__ emb2, __half* __restrict__ h) {
  int node = blockIdx.x;
  int t0 = x[node * 2], t1 = x[node * 2 + 1];
  for (int c = threadIdx.x; c < EMB; c += 256)
    h[(size_t)node * HSH + c] = __float2half(emb1[t0 * EMB + c] + emb2[t1 * EMB + c]);
}

// ---------------- CSR build ----------------
__global__ void count_kernel(const int* __restrict__ ei, int* __restrict__ deg) {
  int e = blockIdx.x * 256 + threadIdx.x;
  if (e < N_EDGES) atomicAdd(&deg[ei[N_EDGES + e]], 1);
}

// fast scan: thread-chunked serial + wave shuffle scan + 16-wave LDS scan.
#define SCH 30   // 1024 * 30 = 30720 >= N_NODES
__global__ __launch_bounds__(1024)
void scan_kernel(const int* __restrict__ deg, int* __restrict__ row_ptr,
                 int* __restrict__ curs) {
  int tid = threadIdx.x;
  int base = tid * SCH;
  int loc[SCH];
  int s = 0;
#pragma unroll
  for (int j = 0; j < SCH; ++j) {
    int i = base + j;
    int v = (i < N_NODES) ? deg[i] : 0;
    loc[j] = s;          // exclusive prefix within chunk
    s += v;
  }
  int lane = tid & 63, wv = tid >> 6;
  int x = s;
#pragma unroll
  for (int o = 1; o < 64; o <<= 1) {
    int y = __shfl_up(x, o, 64);
    if (lane >= o) x += y;
  }
  __shared__ int wsum[16], woff[16];
  if (lane == 63) wsum[wv] = x;
  __syncthreads();
  if (tid == 0) {
    int acc = 0;
    for (int w = 0; w < 16; ++w) { woff[w] = acc; acc += wsum[w]; }
    row_ptr[N_NODES] = acc;
  }
  __syncthreads();
  int excl = woff[wv] + x - s;    // exclusive prefix of this thread's chunk
#pragma unroll
  for (int j = 0; j < SCH; ++j) {
    int i = base + j;
    if (i < N_NODES) { int val = excl + loc[j]; row_ptr[i] = val; curs[i] = val; }
  }
}

__global__ void fill_kernel(const int* __restrict__ ei, const int* __restrict__ ea,
                            int* __restrict__ cursor, int* __restrict__ ebuf) {
  int e = blockIdx.x * 256 + threadIdx.x;
  if (e >= N_EDGES) return;
  int d = ei[N_EDGES + e];
  int pos = atomicAdd(&cursor[d], 1);
  ebuf[pos] = ei[e] * 32 + (ea[2 * e] * 3 + ea[2 * e + 1]);  // src*32 + combo
}

// ---------------- aggregation: fp16 gather-sum, 4x edge unroll ----------------
struct Acc { float x0, y0, x1, y1, x2, y2; };
__device__ __forceinline__ void addEdge(const __half2* __restrict__ hp,
                                        const __half2 (*combo)[150], int t,
                                        int lane, int p2, bool has2, Acc& a) {
  float2 u0 = __half22float2(hp[lane]);
  float2 c0 = __half22float2(combo[t][lane]);
  float2 u1 = __half22float2(hp[lane + 64]);
  float2 c1 = __half22float2(combo[t][lane + 64]);
  a.x0 += u0.x + c0.x;  a.y0 += u0.y + c0.y;
  a.x1 += u1.x + c1.x;  a.y1 += u1.y + c1.y;
  if (has2) {
    float2 u2 = __half22float2(hp[p2]);
    float2 c2 = __half22float2(combo[t][p2]);
    a.x2 += u2.x + c2.x;  a.y2 += u2.y + c2.y;
  }
}

__global__ __launch_bounds__(256)
void aggregate_kernel(const __half* __restrict__ h,
                      const int* __restrict__ row_ptr,
                      const int* __restrict__ ebuf,
                      const float* __restrict__ e1,   // [6,300] this layer
                      const float* __restrict__ e2,   // [3,300] this layer
                      __half* __restrict__ agg) {
  __shared__ __half2 combo[18][150];
  int tid = threadIdx.x;
  for (int idx = tid; idx < 18 * 150; idx += 256) {
    int t = idx / 150, p = idx % 150;
    int a0 = t / 3, a1 = t % 3;
    combo[t][p] = __floats2half2_rn(e1[a0 * EMB + 2 * p]     + e2[a1 * EMB + 2 * p],
                                    e1[a0 * EMB + 2 * p + 1] + e2[a1 * EMB + 2 * p + 1]);
  }
  __syncthreads();
  int wave = tid >> 6, lane = tid & 63;
  int node = blockIdx.x * 4 + wave;
  Acc A = {0,0,0,0,0,0}, B = {0,0,0,0,0,0}, Cc = {0,0,0,0,0,0}, D = {0,0,0,0,0,0};
  int p2 = lane + 128;
  bool has2 = (p2 < 150);
  if (node < N_NODES) {
    int ebeg = row_ptr[node], eend = row_ptr[node + 1];
    int e = ebeg;
    for (; e + 4 <= eend; e += 4) {
      int v0 = ebuf[e], v1 = ebuf[e + 1], v2 = ebuf[e + 2], v3 = ebuf[e + 3];
      const __half2* hp0 = (const __half2*)(h + (size_t)(v0 >> 5) * HSH);
      const __half2* hp1 = (const __half2*)(h + (size_t)(v1 >> 5) * HSH);
      const __half2* hp2 = (const __half2*)(h + (size_t)(v2 >> 5) * HSH);
      const __half2* hp3 = (const __half2*)(h + (size_t)(v3 >> 5) * HSH);
      addEdge(hp0, combo, v0 & 31, lane, p2, has2, A);
      addEdge(hp1, combo, v1 & 31, lane, p2, has2, B);
      addEdge(hp2, combo, v2 & 31, lane, p2, has2, Cc);
      addEdge(hp3, combo, v3 & 31, lane, p2, has2, D);
    }
    for (; e <= eend; ++e) {   // tail edges + self loop
      int s, t;
      if (e < eend) { int v = ebuf[e]; s = v >> 5; t = v & 31; }
      else          { s = node;        t = 4 * 3 + 0; }
      addEdge((const __half2*)(h + (size_t)s * HSH), combo, t, lane, p2, has2, A);
    }
  }
  A.x0 += B.x0 + Cc.x0 + D.x0;  A.y0 += B.y0 + Cc.y0 + D.y0;
  A.x1 += B.x1 + Cc.x1 + D.x1;  A.y1 += B.y1 + Cc.y1 + D.y1;
  A.x2 += B.x2 + Cc.x2 + D.x2;  A.y2 += B.y2 + Cc.y2 + D.y2;
  __half2* op = (__half2*)(agg + (size_t)node * K1);
  op[lane]      = __floats2half2_rn(A.x0, A.y0);
  op[lane + 64] = __floats2half2_rn(A.x1, A.y1);
  if (p2 < 160) op[p2] = has2 ? __floats2half2_rn(A.x2, A.y2)
                              : __floats2half2_rn(0.f, 0.f);   // zero K-pad cols
}

// ---------------- fp16 MFMA GEMM: C = act(A @ B^T + bias) ----------------
// m97-style: global_load_lds width=16 staging, unpadded LDS (stride 32 fp16).
// 128x128 tile, 4 waves of 64x64, K-step 32 via mfma_f32_16x16x32_f16.
// STATS: fuse BN sum/sumsq accumulation (rows < N_NODES, cols < EMB) into epilogue.
template<int RELU, int STATS>
__global__ __launch_bounds__(256, 3)
void gemm_kernel(const __half* __restrict__ A, int lda,
                 const __half* __restrict__ Bt, int ldb,
                 const float* __restrict__ bias,
                 __half* __restrict__ C, int ldc, int K,
                 float* __restrict__ stats) {
  __shared__ _Float16 As[128 * 32];   // unpadded: row = 64 B, lane-order contiguous
  __shared__ _Float16 Bs[128 * 32];
  __shared__ float cs[128], cq[128];
  int tid = threadIdx.x;
  int wave = tid >> 6, lane = tid & 63;
  int wm = wave >> 1, wn = wave & 1;
  int row0 = blockIdx.x * 128, col0 = blockIdx.y * 128;
  int sr = tid >> 2, sc = (tid & 3) * 8;           // staging row / fp16 col chunk
  const __half* ga0 = A + (size_t)(row0 + sr) * lda + sc;
  const __half* ga1 = A + (size_t)(row0 + 64 + sr) * lda + sc;
  const __half* gb0 = Bt + (size_t)(col0 + sr) * ldb + sc;
  const __half* gb1 = Bt + (size_t)(col0 + 64 + sr) * ldb + sc;
  _Float16* la0 = &As[sr * 32 + sc];
  _Float16* la1 = &As[(64 + sr) * 32 + sc];
  _Float16* lb0 = &Bs[sr * 32 + sc];
  _Float16* lb1 = &Bs[(64 + sr) * 32 + sc];

  if (STATS && tid < 128) { cs[tid] = 0.f; cq[tid] = 0.f; }

  floatx4 zero4 = {0.f, 0.f, 0.f, 0.f};
  floatx4 acc[4][4];
#pragma unroll
  for (int i = 0; i < 4; ++i)
#pragma unroll
    for (int j = 0; j < 4; ++j) acc[i][j] = zero4;

  for (int kc = 0; kc < K; kc += 32) {
    gload16(ga0 + kc, la0);
    gload16(ga1 + kc, la1);
    gload16(gb0 + kc, lb0);
    gload16(gb1 + kc, lb1);
    __syncthreads();   // drains vmcnt (global_load_lds) before any LDS read
    half8 af[4], bfr[4];
#pragma unroll
    for (int mi = 0; mi < 4; ++mi)
      af[mi] = *(const half8*)&As[(wm * 64 + mi * 16 + (lane & 15)) * 32 + (lane >> 4) * 8];
#pragma unroll
    for (int ni = 0; ni < 4; ++ni)
      bfr[ni] = *(const half8*)&Bs[(wn * 64 + ni * 16 + (lane & 15)) * 32 + (lane >> 4) * 8];
#pragma unroll
    for (int mi = 0; mi < 4; ++mi)
#pragma unroll
      for (int ni = 0; ni < 4; ++ni)
        acc[mi][ni] = __builtin_amdgcn_mfma_f32_16x16x32_f16(af[mi], bfr[ni], acc[mi][ni], 0, 0, 0);
    __syncthreads();
  }
  // epilogue: C/D layout col=lane&15, row=quad*4+reg
  float ls[4] = {0.f, 0.f, 0.f, 0.f}, lq[4] = {0.f, 0.f, 0.f, 0.f};
#pragma unroll
  for (int mi = 0; mi < 4; ++mi) {
#pragma unroll
    for (int ni = 0; ni < 4; ++ni) {
      int col = col0 + wn * 64 + ni * 16 + (lane & 15);
      float bv = bias[col];
#pragma unroll
      for (int r = 0; r < 4; ++r) {
        int row = row0 + wm * 64 + mi * 16 + (lane >> 4) * 4 + r;
        float v = acc[mi][ni][r] + bv;
        if (RELU) v = fmaxf(v, 0.f);
        C[(size_t)row * ldc + col] = __float2half(v);
        if (STATS && row < N_NODES) { ls[ni] += v; lq[ni] += v * v; }
      }
    }
  }
  if (STATS) {
#pragma unroll
    for (int ni = 0; ni < 4; ++ni) {
      int ci = wn * 64 + ni * 16 + (lane & 15);
      atomicAdd(&cs[ci], ls[ni]);
      atomicAdd(&cq[ci], lq[ni]);
    }
    __syncthreads();
    int col = col0 + tid;
    if (tid < 128 && col < EMB) {
      atomicAdd(&stats[col], cs[tid]);
      atomicAdd(&stats[EMB + col], cq[tid]);
    }
  }
}

// ---------------- batchnorm apply (+relu), half2 vectorized ----------------
__global__ __launch_bounds__(192)
void bn_kernel(const __half* __restrict__ h2, const float* __restrict__ stats,
               const float* __restrict__ gamma, const float* __restrict__ beta,
               __half* __restrict__ hout, float* __restrict__ fout, int relu) {
  int node = blockIdx.x;
  int c2 = threadIdx.x;          // half2 index, 150 active
  if (c2 >= 150) return;
  const float invN = 1.0f / (float)N_NODES;
  int c0 = 2 * c2, c1 = 2 * c2 + 1;
  float mean0 = stats[c0] * invN, mean1 = stats[c1] * invN;
  float var0 = stats[EMB + c0] * invN - mean0 * mean0;
  float var1 = stats[EMB + c1] * invN - mean1 * mean1;
  float sc0 = gamma[c0] * rsqrtf(var0 + 1e-5f);
  float sc1 = gamma[c1] * rsqrtf(var1 + 1e-5f);
  float sh0 = beta[c0] - mean0 * sc0;
  float sh1 = beta[c1] - mean1 * sc1;
  float2 hv = __half22float2(((const __half2*)(h2 + (size_t)node * NP2))[c2]);
  float v0 = hv.x * sc0 + sh0;
  float v1 = hv.y * sc1 + sh1;
  if (relu) { v0 = fmaxf(v0, 0.f); v1 = fmaxf(v1, 0.f); }
  if (hout) {
    ((__half2*)(hout + (size_t)node * HSH))[c2] = __floats2half2_rn(v0, v1);
  } else {
    float2 o; o.x = v0; o.y = v1;
    *(float2*)(fout + (size_t)node * EMB + c0) = o;
  }
}

extern "C" void kernel_launch(void* const* d_in, const int* in_sizes, int n_in,
                              void* d_out, int out_size, void* d_ws, size_t ws_size,
                              hipStream_t stream) {
  const int*   x      = (const int*)d_in[0];
  const int*   ei     = (const int*)d_in[1];
  const int*   ea     = (const int*)d_in[2];
  const float* x_emb1 = (const float*)d_in[3];
  const float* x_emb2 = (const float*)d_in[4];
  const float* edge1  = (const float*)d_in[5];
  const float* edge2  = (const float*)d_in[6];
  const float* W1     = (const float*)d_in[7];
  const float* b1     = (const float*)d_in[8];
  const float* W2     = (const float*)d_in[9];
  const float* b2     = (const float*)d_in[10];
  const float* gamma  = (const float*)d_in[11];
  const float* beta   = (const float*)d_in[12];
  float* out = (float*)d_out;

  char* ws = (char*)d_ws;
  size_t off = 0;
  auto nxt = [&](size_t bytes) {
    void* p = ws + off;
    off += (bytes + 255) & ~(size_t)255;
    return p;
  };
  // Region R: tbuf (fp16 [NPAD][NP1], live gemm1->gemm2) aliases hbuf
  // (fp16 [N_NODES][HSH], read only by aggregate, rewritten by bn).
  size_t tbuf_bytes = (size_t)NPAD * NP1 * 2;        // 38.5 MB
  size_t hbuf_bytes = (size_t)N_NODES * HSH * 2;     // 18.2 MB
  char* R = (char*)nxt(tbuf_bytes > hbuf_bytes ? tbuf_bytes : hbuf_bytes);
  __half* hbuf = (__half*)R;
  __half* tbuf = (__half*)R;
  // Region S: aggb (fp16 [NPAD][K1], live aggregate->gemm1) aliases h2
  // (fp16 [NPAD][NP2], live gemm2->bn).
  size_t agg_bytes = (size_t)NPAD * K1 * 2;          // 19.3 MB
  size_t h2_bytes  = (size_t)NPAD * NP2 * 2;         // 23.1 MB
  char* S = (char*)nxt(agg_bytes > h2_bytes ? agg_bytes : h2_bytes);
  __half* aggb = (__half*)S;
  __half* h2   = (__half*)S;
  __half* w1t  = (__half*)nxt((size_t)LAYERS * NP1 * K1 * 2);
  __half* w2t  = (__half*)nxt((size_t)LAYERS * NP2 * NP1 * 2);
  float*  b1p  = (float*)nxt((size_t)LAYERS * NP1 * 4);
  float*  b2p  = (float*)nxt((size_t)LAYERS * NP2 * 4);
  float*  stat = (float*)nxt((size_t)LAYERS * 2 * EMB * 4);
  int*    deg  = (int*)nxt((size_t)N_NODES * 4);
  int*    rptr = (int*)nxt((size_t)(N_NODES + 1) * 4);
  int*    curs = (int*)nxt((size_t)N_NODES * 4);
  int*    ebuf = (int*)nxt((size_t)N_EDGES * 4);
  // total ~68 MB

  hipMemsetAsync(deg, 0, (size_t)N_NODES * 4, stream);
  hipMemsetAsync(stat, 0, (size_t)LAYERS * 2 * EMB * 4, stream);

  conv_w1t_kernel<<<(LAYERS * NP1 * K1 + 255) / 256, 256, 0, stream>>>(W1, w1t);
  conv_w2t_kernel<<<(LAYERS * NP2 * NP1 + 255) / 256, 256, 0, stream>>>(W2, w2t);
  conv_bias_kernel<<<(LAYERS * (NP1 + NP2) + 255) / 256, 256, 0, stream>>>(b1, b2, b1p, b2p);

  embed_kernel<<<N_NODES, 256, 0, stream>>>(x, x_emb1, x_emb2, hbuf);

  count_kernel<<<(N_EDGES + 255) / 256, 256, 0, stream>>>(ei, deg);
  scan_kernel<<<1, 1024, 0, stream>>>(deg, rptr, curs);
  fill_kernel<<<(N_EDGES + 255) / 256, 256, 0, stream>>>(ei, ea, curs, ebuf);

  for (int l = 0; l < LAYERS; ++l) {
    aggregate_kernel<<<NPAD / 4, 256, 0, stream>>>(
        hbuf, rptr, ebuf, edge1 + (size_t)l * 6 * EMB, edge2 + (size_t)l * 3 * EMB, aggb);
    gemm_kernel<1, 0><<<dim3(NPAD / 128, NP1 / 128), 256, 0, stream>>>(
        aggb, K1, w1t + (size_t)l * NP1 * K1, K1, b1p + l * NP1, tbuf, NP1, K1, nullptr);
    gemm_kernel<0, 1><<<dim3(NPAD / 128, NP2 / 128), 256, 0, stream>>>(
        tbuf, NP1, w2t + (size_t)l * NP2 * NP1, NP1, b2p + l * NP2, h2, NP2, NP1,
        stat + l * 2 * EMB);
    bn_kernel<<<N_NODES, 192, 0, stream>>>(
        h2, stat + l * 2 * EMB, gamma + l * EMB, beta + l * EMB,
        (l < LAYERS - 1) ? hbuf : (__half*)nullptr,
        (l < LAYERS - 1) ? (float*)nullptr : out,
        (l < LAYERS - 1) ? 1 : 0);
  }
}